// Round 5
// baseline (262.148 us; speedup 1.0000x reference)
//
#include <hip/hip_runtime.h>

typedef unsigned short u16;
typedef __bf16 bf16x8 __attribute__((ext_vector_type(8)));
typedef float f32x4 __attribute__((ext_vector_type(4)));

#define DEV __device__ __forceinline__
#define MED3 __builtin_amdgcn_fmed3f
#define MFMA __builtin_amdgcn_mfma_f32_16x16x32_bf16

constexpr int D       = 128;
constexpr int NB      = 2048;     // batch rows
constexpr int C_REAL  = 100000;   // memory rows
constexpr int BN      = 128;      // cols per chunk
constexpr int NSPLIT  = 32;       // column splits
constexpr int CHUNKS  = 25;       // chunks per split
constexpr int CPAD    = NSPLIT * CHUNKS * BN; // 102400 padded cols
constexpr int BM      = 256;      // rows per block in k_dist

// workspace layout (all 256B aligned); total ~28.4 MB
constexpr size_t OFF_MEMB = 0;                                  // CPAD*128 u16
constexpr size_t OFF_MEMN = (size_t)CPAD * D * 2;               // CPAD f32
constexpr size_t OFF_ENCB = OFF_MEMN + (size_t)CPAD * 4;        // NB*128 u16
constexpr size_t OFF_ENCN = OFF_ENCB + (size_t)NB * D * 2;      // NB f32
constexpr size_t OFF_PART = OFF_ENCN + (size_t)NB * 4;          // NB*NSPLIT*10 f32

DEV u16 f2bf(float x) {
    unsigned u = __float_as_uint(x);
    u += 0x7FFFu + ((u >> 16) & 1u);   // RNE to bf16
    return (u16)(u >> 16);
}
DEV float bf2f(u16 b) { return __uint_as_float(((unsigned)b) << 16); }

// ---- top-10 list as named fields: guaranteed register residency ----
struct L10 { float a,b,c,d,e,f,g,h,i,j; };

DEV void linit(L10& L) {
    L.a=L.b=L.c=L.d=L.e=L.f=L.g=L.h=L.i=L.j = __builtin_inff();
}
// branchless insert of x, keeping the 10 smallest (ascending a..j)
DEV void ins(L10& L, float x) {
    L.j = MED3(L.i, L.j, x);
    L.i = MED3(L.h, L.i, x);
    L.h = MED3(L.g, L.h, x);
    L.g = MED3(L.f, L.g, x);
    L.f = MED3(L.e, L.f, x);
    L.e = MED3(L.d, L.e, x);
    L.d = MED3(L.c, L.d, x);
    L.c = MED3(L.b, L.c, x);
    L.b = MED3(L.a, L.b, x);
    L.a = fminf(L.a, x);
}
// guarded insert: exact (key >= L.j cannot change the list)
DEV void insg(L10& L, float x) {
    if (x < L.j) ins(L, x);
}
DEV void mergeX(L10& L, int d) {
    float ta=__shfl_xor(L.a,d), tb=__shfl_xor(L.b,d), tc=__shfl_xor(L.c,d);
    float td=__shfl_xor(L.d,d), te=__shfl_xor(L.e,d), tf=__shfl_xor(L.f,d);
    float tg=__shfl_xor(L.g,d), th=__shfl_xor(L.h,d), ti=__shfl_xor(L.i,d);
    float tj=__shfl_xor(L.j,d);
    ins(L,ta); ins(L,tb); ins(L,tc); ins(L,td); ins(L,te);
    ins(L,tf); ins(L,tg); ins(L,th); ins(L,ti); ins(L,tj);
}
// final-level merge: both lists sorted ascending -> lowest-10 of union is
// elementwise min(L[i], partner[9-i]) (bitonic property). Result order is
// scrambled (bitonic), which is fine for downstream insert-based consumers.
DEV void mergeMin(L10& L, int d) {
    float ra=__shfl_xor(L.a,d), rb=__shfl_xor(L.b,d), rc=__shfl_xor(L.c,d);
    float rd_=__shfl_xor(L.d,d), re=__shfl_xor(L.e,d), rf=__shfl_xor(L.f,d);
    float rg=__shfl_xor(L.g,d), rh=__shfl_xor(L.h,d), ri=__shfl_xor(L.i,d);
    float rj=__shfl_xor(L.j,d);
    L.a=fminf(L.a,rj); L.b=fminf(L.b,ri); L.c=fminf(L.c,rh); L.d=fminf(L.d,rg);
    L.e=fminf(L.e,rf); L.f=fminf(L.f,re); L.g=fminf(L.g,rd_); L.h=fminf(L.h,rc);
    L.i=fminf(L.i,rb); L.j=fminf(L.j,ra);
}
DEV void storeL(const L10& L, float* dst) {
    dst[0]=L.a; dst[1]=L.b; dst[2]=L.c; dst[3]=L.d; dst[4]=L.e;
    dst[5]=L.f; dst[6]=L.g; dst[7]=L.h; dst[8]=L.i; dst[9]=L.j;
}

// ---------------- kernel 1: encoder ----------------
__global__ __launch_bounds__(128)
void k_encoder(const float* __restrict__ state, const float* __restrict__ W1,
               const float* __restrict__ b1, const float* __restrict__ W2,
               const float* __restrict__ b2, u16* __restrict__ encB,
               float* __restrict__ encN)
{
    __shared__ __align__(16) float sA[8][128];
    __shared__ __align__(16) float sH[8][128];
    const int tid = threadIdx.x;
    const int rbase = blockIdx.x * 8;

#pragma unroll
    for (int r = 0; r < 8; ++r)
        sA[r][tid] = state[(size_t)(rbase + r) * D + tid];
    __syncthreads();

    float acc[8];
#pragma unroll
    for (int r = 0; r < 8; ++r) acc[r] = b1[tid];
    for (int d4 = 0; d4 < 32; ++d4) {
        float w0 = W1[(d4 * 4 + 0) * D + tid];
        float w1 = W1[(d4 * 4 + 1) * D + tid];
        float w2 = W1[(d4 * 4 + 2) * D + tid];
        float w3 = W1[(d4 * 4 + 3) * D + tid];
#pragma unroll
        for (int r = 0; r < 8; ++r) {
            float4 sv = *reinterpret_cast<const float4*>(&sA[r][d4 * 4]);
            acc[r] = fmaf(sv.w, w3, fmaf(sv.z, w2, fmaf(sv.y, w1, fmaf(sv.x, w0, acc[r]))));
        }
    }
#pragma unroll
    for (int r = 0; r < 8; ++r) sH[r][tid] = fmaxf(acc[r], 0.f);
    __syncthreads();

#pragma unroll
    for (int r = 0; r < 8; ++r) acc[r] = b2[tid];
    for (int d4 = 0; d4 < 32; ++d4) {
        float w0 = W2[(d4 * 4 + 0) * D + tid];
        float w1 = W2[(d4 * 4 + 1) * D + tid];
        float w2 = W2[(d4 * 4 + 2) * D + tid];
        float w3 = W2[(d4 * 4 + 3) * D + tid];
#pragma unroll
        for (int r = 0; r < 8; ++r) {
            float4 sv = *reinterpret_cast<const float4*>(&sH[r][d4 * 4]);
            acc[r] = fmaf(sv.w, w3, fmaf(sv.z, w2, fmaf(sv.y, w1, fmaf(sv.x, w0, acc[r]))));
        }
    }

#pragma unroll
    for (int r = 0; r < 8; ++r) {
        u16 bb = f2bf(acc[r]);
        encB[(size_t)(rbase + r) * D + tid] = bb;
        float vv = bf2f(bb);
        sA[r][tid] = vv * vv;
    }
    __syncthreads();
    if (tid < 8) {
        float s = 0.f;
        for (int d = 0; d < 128; ++d) s += sA[tid][d];
        encN[rbase + tid] = s;
    }
}

// ---------------- kernel 2: memory -> bf16 + norms (+pad) ----------------
__global__ __launch_bounds__(256)
void k_memprep(const float* __restrict__ mem, u16* __restrict__ memB,
               float* __restrict__ memN)
{
    int g = blockIdx.x * 256 + threadIdx.x;
    int row = g >> 5;
    int l32 = g & 31;
    if (row >= CPAD) return;
    float4 v = make_float4(0.f, 0.f, 0.f, 0.f);
    bool real = row < C_REAL;
    if (real)
        v = *reinterpret_cast<const float4*>(mem + (size_t)row * D + l32 * 4);
    u16 c0 = f2bf(v.x), c1 = f2bf(v.y), c2 = f2bf(v.z), c3 = f2bf(v.w);
    float r0 = bf2f(c0), r1 = bf2f(c1), r2 = bf2f(c2), r3 = bf2f(c3);
    uint2 pk;
    pk.x = (unsigned)c0 | ((unsigned)c1 << 16);
    pk.y = (unsigned)c2 | ((unsigned)c3 << 16);
    *reinterpret_cast<uint2*>(memB + (size_t)row * D + l32 * 4) = pk;
    float s = r0 * r0 + r1 * r1 + r2 * r2 + r3 * r3;
    s += __shfl_xor(s, 16);
    s += __shfl_xor(s, 8);
    s += __shfl_xor(s, 4);
    s += __shfl_xor(s, 2);
    s += __shfl_xor(s, 1);
    if (l32 == 0) memN[row] = real ? s : __builtin_inff();
}

// ---------------- kernel 3: fused distance GEMM + per-split top-10 ----------------
// key per candidate = memN - 2*dot (encN added in k_final; same ordering per row)
__global__ __launch_bounds__(512)
__attribute__((amdgpu_waves_per_eu(2, 2)))
void k_dist(const u16* __restrict__ encB,
            const u16* __restrict__ memB, const float* __restrict__ memN,
            float* __restrict__ partials)
{
    __shared__ __align__(16) unsigned char btile[2][32768]; // double-buffered B chunk

    const int tid = threadIdx.x;
    const int w   = tid >> 6;        // wave 0..7
    const int l   = tid & 63;
    const int l15 = l & 15;
    const int lg  = l >> 4;          // 0..3
    const int split = blockIdx.x;    // 0..31
    const int rbase = blockIdx.y * BM;
    const long cbase0 = (long)split * (CHUNKS * BN);

    // A fragments (K=128) in registers: wave owns rows rbase + w*32 .. +31
    const u16* ap0 = encB + (size_t)(rbase + w * 32 + l15) * D;       // rf=0
    const u16* ap1 = encB + (size_t)(rbase + w * 32 + 16 + l15) * D;  // rf=1
    bf16x8 a00 = *reinterpret_cast<const bf16x8*>(ap0 + 0 * 32 + lg * 8);
    bf16x8 a01 = *reinterpret_cast<const bf16x8*>(ap0 + 1 * 32 + lg * 8);
    bf16x8 a02 = *reinterpret_cast<const bf16x8*>(ap0 + 2 * 32 + lg * 8);
    bf16x8 a03 = *reinterpret_cast<const bf16x8*>(ap0 + 3 * 32 + lg * 8);
    bf16x8 a10 = *reinterpret_cast<const bf16x8*>(ap1 + 0 * 32 + lg * 8);
    bf16x8 a11 = *reinterpret_cast<const bf16x8*>(ap1 + 1 * 32 + lg * 8);
    bf16x8 a12 = *reinterpret_cast<const bf16x8*>(ap1 + 2 * 32 + lg * 8);
    bf16x8 a13 = *reinterpret_cast<const bf16x8*>(ap1 + 3 * 32 + lg * 8);

    L10 T0,T1,T2,T3,T4,T5,T6,T7;
    linit(T0); linit(T1); linit(T2); linit(T3);
    linit(T4); linit(T5); linit(T6); linit(T7);

    // LDS content: LDS[x] = chunk[x ^ S(x)], S(x) = ((x>>8)&7)<<4 (involution;
    // S's input bits [10:8] are untouched by the XOR of bits [6:4]).
    // Staging via global_load_lds: LDS dest is wave-uniform base + lane*16
    // (linear), swizzle applied to the per-lane GLOBAL source address.
    int wsrcoff[4];
#pragma unroll
    for (int u = 0; u < 4; ++u) {
        int p = (u << 13) | (tid << 4);
        wsrcoff[u] = p ^ (((p >> 8) & 7) << 4);
    }
    // read addresses: q = col*256 + ks*64 + lg*16, col = cg*16 + l15
    // LDS addr = q ^ ((col&7)<<4); per-lane base (cg=0), ks variants:
    const int rbl = ((l15 << 8) | (lg << 4)) ^ ((l15 & 7) << 4);
    const int off0 = rbl ^ (0 << 6);
    const int off1 = rbl ^ (1 << 6);
    const int off2 = rbl ^ (2 << 6);
    const int off3 = rbl ^ (3 << 6);

#define STAGE(B, CH) do { \
    const unsigned char* sb_ = (const unsigned char*)(memB + (cbase0 + (long)(CH) * BN) * D); \
    __builtin_amdgcn_global_load_lds( \
        (const __attribute__((address_space(1))) unsigned char*)(sb_ + wsrcoff[0]), \
        (__attribute__((address_space(3))) unsigned char*)(&btile[0][0] + (((B) << 15) | (0 << 13) | (w << 10))), 16, 0, 0); \
    __builtin_amdgcn_global_load_lds( \
        (const __attribute__((address_space(1))) unsigned char*)(sb_ + wsrcoff[1]), \
        (__attribute__((address_space(3))) unsigned char*)(&btile[0][0] + (((B) << 15) | (1 << 13) | (w << 10))), 16, 0, 0); \
    __builtin_amdgcn_global_load_lds( \
        (const __attribute__((address_space(1))) unsigned char*)(sb_ + wsrcoff[2]), \
        (__attribute__((address_space(3))) unsigned char*)(&btile[0][0] + (((B) << 15) | (2 << 13) | (w << 10))), 16, 0, 0); \
    __builtin_amdgcn_global_load_lds( \
        (const __attribute__((address_space(1))) unsigned char*)(sb_ + wsrcoff[3]), \
        (__attribute__((address_space(3))) unsigned char*)(&btile[0][0] + (((B) << 15) | (3 << 13) | (w << 10))), 16, 0, 0); \
} while (0)

#define KEY8(A0, A1, MN) do { \
    float k0_ = fmaf(-2.0f, (A0)[0], (MN)); \
    float k1_ = fmaf(-2.0f, (A0)[1], (MN)); \
    float k2_ = fmaf(-2.0f, (A0)[2], (MN)); \
    float k3_ = fmaf(-2.0f, (A0)[3], (MN)); \
    float k4_ = fmaf(-2.0f, (A1)[0], (MN)); \
    float k5_ = fmaf(-2.0f, (A1)[1], (MN)); \
    float k6_ = fmaf(-2.0f, (A1)[2], (MN)); \
    float k7_ = fmaf(-2.0f, (A1)[3], (MN)); \
    insg(T0, k0_); insg(T1, k1_); insg(T2, k2_); insg(T3, k3_); \
    insg(T4, k4_); insg(T5, k5_); insg(T6, k6_); insg(T7, k7_); \
} while (0)

#define DO_CG(CGI, MNV) do { \
    bf16x8 q0 = *reinterpret_cast<const bf16x8*>(bp + (off0 + ((CGI) << 12))); \
    bf16x8 q1 = *reinterpret_cast<const bf16x8*>(bp + (off1 + ((CGI) << 12))); \
    bf16x8 q2 = *reinterpret_cast<const bf16x8*>(bp + (off2 + ((CGI) << 12))); \
    bf16x8 q3 = *reinterpret_cast<const bf16x8*>(bp + (off3 + ((CGI) << 12))); \
    f32x4 ac0 = {0.f, 0.f, 0.f, 0.f}; \
    f32x4 ac1 = {0.f, 0.f, 0.f, 0.f}; \
    ac0 = MFMA(a00, q0, ac0, 0, 0, 0); \
    ac1 = MFMA(a10, q0, ac1, 0, 0, 0); \
    ac0 = MFMA(a01, q1, ac0, 0, 0, 0); \
    ac1 = MFMA(a11, q1, ac1, 0, 0, 0); \
    ac0 = MFMA(a02, q2, ac0, 0, 0, 0); \
    ac1 = MFMA(a12, q2, ac1, 0, 0, 0); \
    ac0 = MFMA(a03, q3, ac0, 0, 0, 0); \
    ac1 = MFMA(a13, q3, ac1, 0, 0, 0); \
    KEY8(ac0, ac1, (MNV)); \
} while (0)

    // prologue: stage chunk 0 into buffer 0; barrier drains vmcnt
    STAGE(0, 0);
    __syncthreads();

#pragma unroll 1
    for (int ch = 0; ch < CHUNKS; ++ch) {
        // issue next chunk's DMA into the other buffer (completes by the
        // barrier at the end of this iteration — a full chunk of cover)
        if (ch + 1 < CHUNKS) STAGE((ch + 1) & 1, ch + 1);

        const long cbase = cbase0 + (long)ch * BN;
        const float* mnp = memN + cbase + l15;
        float mn0 = mnp[0 * 16], mn1 = mnp[1 * 16], mn2 = mnp[2 * 16], mn3 = mnp[3 * 16];
        float mn4 = mnp[4 * 16], mn5 = mnp[5 * 16], mn6 = mnp[6 * 16], mn7 = mnp[7 * 16];

        const unsigned char* bp = &btile[ch & 1][0];
        DO_CG(0, mn0);
        DO_CG(1, mn1);
        DO_CG(2, mn2);
        DO_CG(3, mn3);
        DO_CG(4, mn4);
        DO_CG(5, mn5);
        DO_CG(6, mn6);
        DO_CG(7, mn7);
        __syncthreads();   // implicit s_waitcnt vmcnt(0): next buffer ready
    }

    // exact merge across the 16 col-lanes of each row: 3 insert-merge levels
    // (lists stay sorted) + 1 cheap min-level, then lane l15==0 stores.
#define MERGE_STORE(T, LI) do { \
    mergeX(T, 1); mergeX(T, 2); mergeX(T, 4); mergeMin(T, 8); \
    if (l15 == 0) { \
        int row = rbase + w * 32 + ((LI) >> 2) * 16 + lg * 4 + ((LI) & 3); \
        storeL(T, partials + (size_t)row * (NSPLIT * 10) + split * 10); \
    } \
} while (0)

    MERGE_STORE(T0, 0);
    MERGE_STORE(T1, 1);
    MERGE_STORE(T2, 2);
    MERGE_STORE(T3, 3);
    MERGE_STORE(T4, 4);
    MERGE_STORE(T5, 5);
    MERGE_STORE(T6, 6);
    MERGE_STORE(T7, 7);
}

// ---------------- kernel 4: final merge + mean of sqrt (1 wave / row) ----------------
__global__ __launch_bounds__(256)
void k_final(const float* __restrict__ partials, const float* __restrict__ encN,
             float* __restrict__ out)
{
    const int w = threadIdx.x >> 6;
    const int l = threadIdx.x & 63;
    const int row = blockIdx.x * 4 + w;

    L10 L;
    linit(L);
    const float* p = partials + (size_t)row * (NSPLIT * 10) + l * 5;
    ins(L, p[0]); ins(L, p[1]); ins(L, p[2]); ins(L, p[3]); ins(L, p[4]);
    mergeX(L, 1); mergeX(L, 2); mergeX(L, 4);
    mergeX(L, 8); mergeX(L, 16); mergeMin(L, 32);
    if (l == 0) {
        float en = encN[row];
        float s = 0.f;
        s += sqrtf(fmaxf(en + L.a, 1e-12f));
        s += sqrtf(fmaxf(en + L.b, 1e-12f));
        s += sqrtf(fmaxf(en + L.c, 1e-12f));
        s += sqrtf(fmaxf(en + L.d, 1e-12f));
        s += sqrtf(fmaxf(en + L.e, 1e-12f));
        s += sqrtf(fmaxf(en + L.f, 1e-12f));
        s += sqrtf(fmaxf(en + L.g, 1e-12f));
        s += sqrtf(fmaxf(en + L.h, 1e-12f));
        s += sqrtf(fmaxf(en + L.i, 1e-12f));
        s += sqrtf(fmaxf(en + L.j, 1e-12f));
        out[row] = s * 0.1f;
    }
}

extern "C" void kernel_launch(void* const* d_in, const int* in_sizes, int n_in,
                              void* d_out, int out_size, void* d_ws, size_t ws_size,
                              hipStream_t stream)
{
    const float* state = (const float*)d_in[0];
    const float* W1    = (const float*)d_in[1];
    const float* b1    = (const float*)d_in[2];
    const float* W2    = (const float*)d_in[3];
    const float* b2    = (const float*)d_in[4];
    const float* mem   = (const float*)d_in[5];
    float* out = (float*)d_out;
    char* ws = (char*)d_ws;
    u16*   memB = (u16*)(ws + OFF_MEMB);
    float* memN = (float*)(ws + OFF_MEMN);
    u16*   encB = (u16*)(ws + OFF_ENCB);
    float* encN = (float*)(ws + OFF_ENCN);
    float* partials = (float*)(ws + OFF_PART);

    hipLaunchKernelGGL(k_encoder, dim3(NB / 8), dim3(128), 0, stream,
                       state, W1, b1, W2, b2, encB, encN);
    hipLaunchKernelGGL(k_memprep, dim3(CPAD * 32 / 256), dim3(256), 0, stream,
                       mem, memB, memN);
    hipLaunchKernelGGL(k_dist, dim3(NSPLIT, NB / BM), dim3(512), 0, stream,
                       encB, memB, memN, partials);
    hipLaunchKernelGGL(k_final, dim3(NB / 4), dim3(256), 0, stream,
                       partials, encN, out);
}

// Round 6
// 224.863 us; speedup vs baseline: 1.1658x; 1.1658x over previous
//
#include <hip/hip_runtime.h>

typedef unsigned short u16;
typedef __bf16 bf16x8 __attribute__((ext_vector_type(8)));
typedef float f32x4 __attribute__((ext_vector_type(4)));

#define DEV __device__ __forceinline__
#define MFMA __builtin_amdgcn_mfma_f32_16x16x32_bf16

constexpr int D       = 128;
constexpr int NB      = 2048;     // batch rows
constexpr int C_REAL  = 100000;   // memory rows
constexpr int BN      = 128;      // cols per chunk
constexpr int NSPLIT  = 32;       // column splits
constexpr int CHUNKS  = 25;       // chunks per split
constexpr int CPAD    = NSPLIT * CHUNKS * BN; // 102400 padded cols
constexpr int BM      = 256;      // rows per block in k_dist

// workspace layout (all 256B aligned); total ~28.4 MB
constexpr size_t OFF_MEMB = 0;                                  // CPAD*128 u16
constexpr size_t OFF_MEMN = (size_t)CPAD * D * 2;               // CPAD f32
constexpr size_t OFF_ENCB = OFF_MEMN + (size_t)CPAD * 4;        // NB*128 u16
constexpr size_t OFF_ENCN = OFF_ENCB + (size_t)NB * D * 2;      // NB f32
constexpr size_t OFF_PART = OFF_ENCN + (size_t)NB * 4;          // NB*NSPLIT*10 f32

DEV u16 f2bf(float x) {
    unsigned u = __float_as_uint(x);
    u += 0x7FFFu + ((u >> 16) & 1u);   // RNE to bf16
    return (u16)(u >> 16);
}
DEV float bf2f(u16 b) { return __uint_as_float(((unsigned)b) << 16); }

// ---- top-10 list as named fields ----
struct L10 { float a,b,c,d,e,f,g,h,i,j; };

DEV void linit(L10& L) {
    L.a=L.b=L.c=L.d=L.e=L.f=L.g=L.h=L.i=L.j = __builtin_inff();
}
// branchless insert of x keeping the 10 smallest (ascending a..j).
// Single asm block, "+v" constraints -> arch-VGPR residency (no AGPR moves).
// No intra-block RAW hazards: every instruction reads only pre-update values.
DEV void ins(L10& L, float x) {
    asm("v_med3_f32 %0, %1, %0, %10\n\t"   // j = med3(i, j, x)
        "v_med3_f32 %1, %2, %1, %10\n\t"   // i = med3(h, i, x)
        "v_med3_f32 %2, %3, %2, %10\n\t"   // h = med3(g, h, x)
        "v_med3_f32 %3, %4, %3, %10\n\t"   // g = med3(f, g, x)
        "v_med3_f32 %4, %5, %4, %10\n\t"   // f = med3(e, f, x)
        "v_med3_f32 %5, %6, %5, %10\n\t"   // e = med3(d, e, x)
        "v_med3_f32 %6, %7, %6, %10\n\t"   // d = med3(c, d, x)
        "v_med3_f32 %7, %8, %7, %10\n\t"   // c = med3(b, c, x)
        "v_med3_f32 %8, %9, %8, %10\n\t"   // b = med3(a, b, x)
        "v_min_f32  %9, %9, %10"           // a = min(a, x)
        : "+v"(L.j), "+v"(L.i), "+v"(L.h), "+v"(L.g), "+v"(L.f),
          "+v"(L.e), "+v"(L.d), "+v"(L.c), "+v"(L.b), "+v"(L.a)
        : "v"(x));
}
DEV void mergeX(L10& L, int d) {
    float ta=__shfl_xor(L.a,d), tb=__shfl_xor(L.b,d), tc=__shfl_xor(L.c,d);
    float td=__shfl_xor(L.d,d), te=__shfl_xor(L.e,d), tf=__shfl_xor(L.f,d);
    float tg=__shfl_xor(L.g,d), th=__shfl_xor(L.h,d), ti=__shfl_xor(L.i,d);
    float tj=__shfl_xor(L.j,d);
    ins(L,ta); ins(L,tb); ins(L,tc); ins(L,td); ins(L,te);
    ins(L,tf); ins(L,tg); ins(L,th); ins(L,ti); ins(L,tj);
}
// final-level merge: both lists sorted ascending -> lowest-10 of union is
// elementwise min(L[i], partner[9-i]) (bitonic property; output order scrambled).
DEV void mergeMin(L10& L, int d) {
    float ra=__shfl_xor(L.a,d), rb=__shfl_xor(L.b,d), rc=__shfl_xor(L.c,d);
    float rd_=__shfl_xor(L.d,d), re=__shfl_xor(L.e,d), rf=__shfl_xor(L.f,d);
    float rg=__shfl_xor(L.g,d), rh=__shfl_xor(L.h,d), ri=__shfl_xor(L.i,d);
    float rj=__shfl_xor(L.j,d);
    L.a=fminf(L.a,rj); L.b=fminf(L.b,ri); L.c=fminf(L.c,rh); L.d=fminf(L.d,rg);
    L.e=fminf(L.e,rf); L.f=fminf(L.f,re); L.g=fminf(L.g,rd_); L.h=fminf(L.h,rc);
    L.i=fminf(L.i,rb); L.j=fminf(L.j,ra);
}
DEV void storeL(const L10& L, float* dst) {
    dst[0]=L.a; dst[1]=L.b; dst[2]=L.c; dst[3]=L.d; dst[4]=L.e;
    dst[5]=L.f; dst[6]=L.g; dst[7]=L.h; dst[8]=L.i; dst[9]=L.j;
}

// ---------------- kernel 1: encoder ----------------
__global__ __launch_bounds__(128)
void k_encoder(const float* __restrict__ state, const float* __restrict__ W1,
               const float* __restrict__ b1, const float* __restrict__ W2,
               const float* __restrict__ b2, u16* __restrict__ encB,
               float* __restrict__ encN)
{
    __shared__ __align__(16) float sA[8][128];
    __shared__ __align__(16) float sH[8][128];
    const int tid = threadIdx.x;
    const int rbase = blockIdx.x * 8;

#pragma unroll
    for (int r = 0; r < 8; ++r)
        sA[r][tid] = state[(size_t)(rbase + r) * D + tid];
    __syncthreads();

    float acc[8];
#pragma unroll
    for (int r = 0; r < 8; ++r) acc[r] = b1[tid];
    for (int d4 = 0; d4 < 32; ++d4) {
        float w0 = W1[(d4 * 4 + 0) * D + tid];
        float w1 = W1[(d4 * 4 + 1) * D + tid];
        float w2 = W1[(d4 * 4 + 2) * D + tid];
        float w3 = W1[(d4 * 4 + 3) * D + tid];
#pragma unroll
        for (int r = 0; r < 8; ++r) {
            float4 sv = *reinterpret_cast<const float4*>(&sA[r][d4 * 4]);
            acc[r] = fmaf(sv.w, w3, fmaf(sv.z, w2, fmaf(sv.y, w1, fmaf(sv.x, w0, acc[r]))));
        }
    }
#pragma unroll
    for (int r = 0; r < 8; ++r) sH[r][tid] = fmaxf(acc[r], 0.f);
    __syncthreads();

#pragma unroll
    for (int r = 0; r < 8; ++r) acc[r] = b2[tid];
    for (int d4 = 0; d4 < 32; ++d4) {
        float w0 = W2[(d4 * 4 + 0) * D + tid];
        float w1 = W2[(d4 * 4 + 1) * D + tid];
        float w2 = W2[(d4 * 4 + 2) * D + tid];
        float w3 = W2[(d4 * 4 + 3) * D + tid];
#pragma unroll
        for (int r = 0; r < 8; ++r) {
            float4 sv = *reinterpret_cast<const float4*>(&sH[r][d4 * 4]);
            acc[r] = fmaf(sv.w, w3, fmaf(sv.z, w2, fmaf(sv.y, w1, fmaf(sv.x, w0, acc[r]))));
        }
    }

#pragma unroll
    for (int r = 0; r < 8; ++r) {
        u16 bb = f2bf(acc[r]);
        encB[(size_t)(rbase + r) * D + tid] = bb;
        float vv = bf2f(bb);
        sA[r][tid] = vv * vv;
    }
    __syncthreads();
    if (tid < 8) {
        float s = 0.f;
        for (int d = 0; d < 128; ++d) s += sA[tid][d];
        encN[rbase + tid] = s;
    }
}

// ---------------- kernel 2: memory -> bf16 + norms (+pad) ----------------
__global__ __launch_bounds__(256)
void k_memprep(const float* __restrict__ mem, u16* __restrict__ memB,
               float* __restrict__ memN)
{
    int g = blockIdx.x * 256 + threadIdx.x;
    int row = g >> 5;
    int l32 = g & 31;
    if (row >= CPAD) return;
    float4 v = make_float4(0.f, 0.f, 0.f, 0.f);
    bool real = row < C_REAL;
    if (real)
        v = *reinterpret_cast<const float4*>(mem + (size_t)row * D + l32 * 4);
    u16 c0 = f2bf(v.x), c1 = f2bf(v.y), c2 = f2bf(v.z), c3 = f2bf(v.w);
    float r0 = bf2f(c0), r1 = bf2f(c1), r2 = bf2f(c2), r3 = bf2f(c3);
    uint2 pk;
    pk.x = (unsigned)c0 | ((unsigned)c1 << 16);
    pk.y = (unsigned)c2 | ((unsigned)c3 << 16);
    *reinterpret_cast<uint2*>(memB + (size_t)row * D + l32 * 4) = pk;
    float s = r0 * r0 + r1 * r1 + r2 * r2 + r3 * r3;
    s += __shfl_xor(s, 16);
    s += __shfl_xor(s, 8);
    s += __shfl_xor(s, 4);
    s += __shfl_xor(s, 2);
    s += __shfl_xor(s, 1);
    if (l32 == 0) memN[row] = real ? s : __builtin_inff();
}

// ---------------- kernel 3: fused distance GEMM + per-split top-10 ----------------
// key per candidate = memN - 2*dot (encN added in k_final; same ordering per row)
__global__ __launch_bounds__(512)
__attribute__((amdgpu_waves_per_eu(2, 2)))
void k_dist(const u16* __restrict__ encB,
            const u16* __restrict__ memB, const float* __restrict__ memN,
            float* __restrict__ partials)
{
    __shared__ __align__(16) unsigned char btile[2][32768]; // double-buffered B chunk

    const int tid = threadIdx.x;
    const int w   = tid >> 6;        // wave 0..7
    const int l   = tid & 63;
    const int l15 = l & 15;
    const int lg  = l >> 4;          // 0..3
    const int split = blockIdx.x;    // 0..31
    const int rbase = blockIdx.y * BM;
    const long cbase0 = (long)split * (CHUNKS * BN);

    // A fragments (K=128) in registers: wave owns rows rbase + w*32 .. +31
    const u16* ap0 = encB + (size_t)(rbase + w * 32 + l15) * D;       // rf=0
    const u16* ap1 = encB + (size_t)(rbase + w * 32 + 16 + l15) * D;  // rf=1
    bf16x8 a00 = *reinterpret_cast<const bf16x8*>(ap0 + 0 * 32 + lg * 8);
    bf16x8 a01 = *reinterpret_cast<const bf16x8*>(ap0 + 1 * 32 + lg * 8);
    bf16x8 a02 = *reinterpret_cast<const bf16x8*>(ap0 + 2 * 32 + lg * 8);
    bf16x8 a03 = *reinterpret_cast<const bf16x8*>(ap0 + 3 * 32 + lg * 8);
    bf16x8 a10 = *reinterpret_cast<const bf16x8*>(ap1 + 0 * 32 + lg * 8);
    bf16x8 a11 = *reinterpret_cast<const bf16x8*>(ap1 + 1 * 32 + lg * 8);
    bf16x8 a12 = *reinterpret_cast<const bf16x8*>(ap1 + 2 * 32 + lg * 8);
    bf16x8 a13 = *reinterpret_cast<const bf16x8*>(ap1 + 3 * 32 + lg * 8);

    L10 T0,T1,T2,T3,T4,T5,T6,T7;
    linit(T0); linit(T1); linit(T2); linit(T3);
    linit(T4); linit(T5); linit(T6); linit(T7);

    // LDS content: LDS[x] = chunk[x ^ S(x)], S(x) = ((x>>8)&7)<<4 (involution;
    // S's input bits [10:8] are untouched by the XOR of bits [6:4]).
    // Staging via global_load_lds: LDS dest is wave-uniform base + lane*16
    // (linear), swizzle applied to the per-lane GLOBAL source address.
    int wsrcoff[4];
#pragma unroll
    for (int u = 0; u < 4; ++u) {
        int p = (u << 13) | (tid << 4);
        wsrcoff[u] = p ^ (((p >> 8) & 7) << 4);
    }
    // read addresses: q = col*256 + ks*64 + lg*16, col = cg*16 + l15
    // LDS addr = q ^ ((col&7)<<4); per-lane base (cg=0), ks variants:
    const int rbl = ((l15 << 8) | (lg << 4)) ^ ((l15 & 7) << 4);
    const int off0 = rbl ^ (0 << 6);
    const int off1 = rbl ^ (1 << 6);
    const int off2 = rbl ^ (2 << 6);
    const int off3 = rbl ^ (3 << 6);

#define STAGE(B, CH) do { \
    const unsigned char* sb_ = (const unsigned char*)(memB + (cbase0 + (long)(CH) * BN) * D); \
    __builtin_amdgcn_global_load_lds( \
        (const __attribute__((address_space(1))) unsigned char*)(sb_ + wsrcoff[0]), \
        (__attribute__((address_space(3))) unsigned char*)(&btile[0][0] + (((B) << 15) | (0 << 13) | (w << 10))), 16, 0, 0); \
    __builtin_amdgcn_global_load_lds( \
        (const __attribute__((address_space(1))) unsigned char*)(sb_ + wsrcoff[1]), \
        (__attribute__((address_space(3))) unsigned char*)(&btile[0][0] + (((B) << 15) | (1 << 13) | (w << 10))), 16, 0, 0); \
    __builtin_amdgcn_global_load_lds( \
        (const __attribute__((address_space(1))) unsigned char*)(sb_ + wsrcoff[2]), \
        (__attribute__((address_space(3))) unsigned char*)(&btile[0][0] + (((B) << 15) | (2 << 13) | (w << 10))), 16, 0, 0); \
    __builtin_amdgcn_global_load_lds( \
        (const __attribute__((address_space(1))) unsigned char*)(sb_ + wsrcoff[3]), \
        (__attribute__((address_space(3))) unsigned char*)(&btile[0][0] + (((B) << 15) | (3 << 13) | (w << 10))), 16, 0, 0); \
} while (0)

#define KEY8(A0, A1, MN) do { \
    float k0_ = fmaf(-2.0f, (A0)[0], (MN)); \
    float k1_ = fmaf(-2.0f, (A0)[1], (MN)); \
    float k2_ = fmaf(-2.0f, (A0)[2], (MN)); \
    float k3_ = fmaf(-2.0f, (A0)[3], (MN)); \
    float k4_ = fmaf(-2.0f, (A1)[0], (MN)); \
    float k5_ = fmaf(-2.0f, (A1)[1], (MN)); \
    float k6_ = fmaf(-2.0f, (A1)[2], (MN)); \
    float k7_ = fmaf(-2.0f, (A1)[3], (MN)); \
    ins(T0, k0_); ins(T1, k1_); ins(T2, k2_); ins(T3, k3_); \
    ins(T4, k4_); ins(T5, k5_); ins(T6, k6_); ins(T7, k7_); \
} while (0)

#define DO_CG(CGI, MNV) do { \
    bf16x8 q0 = *reinterpret_cast<const bf16x8*>(bp + (off0 + ((CGI) << 12))); \
    bf16x8 q1 = *reinterpret_cast<const bf16x8*>(bp + (off1 + ((CGI) << 12))); \
    bf16x8 q2 = *reinterpret_cast<const bf16x8*>(bp + (off2 + ((CGI) << 12))); \
    bf16x8 q3 = *reinterpret_cast<const bf16x8*>(bp + (off3 + ((CGI) << 12))); \
    f32x4 ac0 = {0.f, 0.f, 0.f, 0.f}; \
    f32x4 ac1 = {0.f, 0.f, 0.f, 0.f}; \
    ac0 = MFMA(a00, q0, ac0, 0, 0, 0); \
    ac1 = MFMA(a10, q0, ac1, 0, 0, 0); \
    ac0 = MFMA(a01, q1, ac0, 0, 0, 0); \
    ac1 = MFMA(a11, q1, ac1, 0, 0, 0); \
    ac0 = MFMA(a02, q2, ac0, 0, 0, 0); \
    ac1 = MFMA(a12, q2, ac1, 0, 0, 0); \
    ac0 = MFMA(a03, q3, ac0, 0, 0, 0); \
    ac1 = MFMA(a13, q3, ac1, 0, 0, 0); \
    KEY8(ac0, ac1, (MNV)); \
} while (0)

    // prologue: stage chunk 0 into buffer 0; barrier drains vmcnt
    STAGE(0, 0);
    __syncthreads();

#pragma unroll 1
    for (int ch = 0; ch < CHUNKS; ++ch) {
        // issue next chunk's DMA into the other buffer (completes by the
        // barrier at the end of this iteration — a full chunk of cover)
        if (ch + 1 < CHUNKS) STAGE((ch + 1) & 1, ch + 1);

        const long cbase = cbase0 + (long)ch * BN;
        const float* mnp = memN + cbase + l15;
        float mn0 = mnp[0 * 16], mn1 = mnp[1 * 16], mn2 = mnp[2 * 16], mn3 = mnp[3 * 16];
        float mn4 = mnp[4 * 16], mn5 = mnp[5 * 16], mn6 = mnp[6 * 16], mn7 = mnp[7 * 16];

        const unsigned char* bp = &btile[ch & 1][0];
        DO_CG(0, mn0);
        DO_CG(1, mn1);
        DO_CG(2, mn2);
        DO_CG(3, mn3);
        DO_CG(4, mn4);
        DO_CG(5, mn5);
        DO_CG(6, mn6);
        DO_CG(7, mn7);
        __syncthreads();   // implicit s_waitcnt vmcnt(0): next buffer ready
    }

    // exact merge across the 16 col-lanes of each row: 3 insert-merge levels
    // (lists stay sorted) + 1 cheap min-level, then lane l15==0 stores.
#define MERGE_STORE(T, LI) do { \
    mergeX(T, 1); mergeX(T, 2); mergeX(T, 4); mergeMin(T, 8); \
    if (l15 == 0) { \
        int row = rbase + w * 32 + ((LI) >> 2) * 16 + lg * 4 + ((LI) & 3); \
        storeL(T, partials + (size_t)row * (NSPLIT * 10) + split * 10); \
    } \
} while (0)

    MERGE_STORE(T0, 0);
    MERGE_STORE(T1, 1);
    MERGE_STORE(T2, 2);
    MERGE_STORE(T3, 3);
    MERGE_STORE(T4, 4);
    MERGE_STORE(T5, 5);
    MERGE_STORE(T6, 6);
    MERGE_STORE(T7, 7);
}

// ---------------- kernel 4: final merge + mean of sqrt (1 wave / row) ----------------
__global__ __launch_bounds__(256)
void k_final(const float* __restrict__ partials, const float* __restrict__ encN,
             float* __restrict__ out)
{
    const int w = threadIdx.x >> 6;
    const int l = threadIdx.x & 63;
    const int row = blockIdx.x * 4 + w;

    L10 L;
    linit(L);
    const float* p = partials + (size_t)row * (NSPLIT * 10) + l * 5;
    ins(L, p[0]); ins(L, p[1]); ins(L, p[2]); ins(L, p[3]); ins(L, p[4]);
    mergeX(L, 1); mergeX(L, 2); mergeX(L, 4);
    mergeX(L, 8); mergeX(L, 16); mergeMin(L, 32);
    if (l == 0) {
        float en = encN[row];
        float s = 0.f;
        s += sqrtf(fmaxf(en + L.a, 1e-12f));
        s += sqrtf(fmaxf(en + L.b, 1e-12f));
        s += sqrtf(fmaxf(en + L.c, 1e-12f));
        s += sqrtf(fmaxf(en + L.d, 1e-12f));
        s += sqrtf(fmaxf(en + L.e, 1e-12f));
        s += sqrtf(fmaxf(en + L.f, 1e-12f));
        s += sqrtf(fmaxf(en + L.g, 1e-12f));
        s += sqrtf(fmaxf(en + L.h, 1e-12f));
        s += sqrtf(fmaxf(en + L.i, 1e-12f));
        s += sqrtf(fmaxf(en + L.j, 1e-12f));
        out[row] = s * 0.1f;
    }
}

extern "C" void kernel_launch(void* const* d_in, const int* in_sizes, int n_in,
                              void* d_out, int out_size, void* d_ws, size_t ws_size,
                              hipStream_t stream)
{
    const float* state = (const float*)d_in[0];
    const float* W1    = (const float*)d_in[1];
    const float* b1    = (const float*)d_in[2];
    const float* W2    = (const float*)d_in[3];
    const float* b2    = (const float*)d_in[4];
    const float* mem   = (const float*)d_in[5];
    float* out = (float*)d_out;
    char* ws = (char*)d_ws;
    u16*   memB = (u16*)(ws + OFF_MEMB);
    float* memN = (float*)(ws + OFF_MEMN);
    u16*   encB = (u16*)(ws + OFF_ENCB);
    float* encN = (float*)(ws + OFF_ENCN);
    float* partials = (float*)(ws + OFF_PART);

    hipLaunchKernelGGL(k_encoder, dim3(NB / 8), dim3(128), 0, stream,
                       state, W1, b1, W2, b2, encB, encN);
    hipLaunchKernelGGL(k_memprep, dim3(CPAD * 32 / 256), dim3(256), 0, stream,
                       mem, memB, memN);
    hipLaunchKernelGGL(k_dist, dim3(NSPLIT, NB / BM), dim3(512), 0, stream,
                       encB, memB, memN, partials);
    hipLaunchKernelGGL(k_final, dim3(NB / 4), dim3(256), 0, stream,
                       partials, encN, out);
}

// Round 9
// 222.618 us; speedup vs baseline: 1.1776x; 1.0101x over previous
//
#include <hip/hip_runtime.h>

typedef unsigned short u16;
typedef __bf16 bf16x8 __attribute__((ext_vector_type(8)));
typedef float f32x4 __attribute__((ext_vector_type(4)));

#define DEV __device__ __forceinline__
#define MFMA __builtin_amdgcn_mfma_f32_16x16x32_bf16

constexpr int D       = 128;
constexpr int NB      = 2048;     // batch rows
constexpr int C_REAL  = 100000;   // memory rows
constexpr int BN      = 128;      // cols per chunk
constexpr int NSPLIT  = 32;       // column splits
constexpr int CHUNKS  = 25;       // chunks per split
constexpr int CPAD    = NSPLIT * CHUNKS * BN; // 102400 padded cols
constexpr int BM      = 128;      // rows per block in k_dist (4 waves, 2 blocks/CU)

// workspace layout (all 256B aligned); total ~28.4 MB
constexpr size_t OFF_MEMB = 0;                                  // CPAD*128 u16
constexpr size_t OFF_MEMN = (size_t)CPAD * D * 2;               // CPAD f32
constexpr size_t OFF_ENCB = OFF_MEMN + (size_t)CPAD * 4;        // NB*128 u16
constexpr size_t OFF_ENCN = OFF_ENCB + (size_t)NB * D * 2;      // NB f32
constexpr size_t OFF_PART = OFF_ENCN + (size_t)NB * 4;          // NB*NSPLIT*10 f32

DEV u16 f2bf(float x) {
    unsigned u = __float_as_uint(x);
    u += 0x7FFFu + ((u >> 16) & 1u);   // RNE to bf16
    return (u16)(u >> 16);
}
DEV float bf2f(u16 b) { return __uint_as_float(((unsigned)b) << 16); }

// ---- top-10 list as named fields ----
struct L10 { float a,b,c,d,e,f,g,h,i,j; };

DEV void linit(L10& L) {
    L.a=L.b=L.c=L.d=L.e=L.f=L.g=L.h=L.i=L.j = __builtin_inff();
}
// branchless insert of x keeping the 10 smallest (ascending a..j).
// Single asm block, "+v" constraints -> arch-VGPR residency (no AGPR moves).
// No intra-block RAW hazards: every instruction reads only pre-update values.
DEV void ins(L10& L, float x) {
    asm("v_med3_f32 %0, %1, %0, %10\n\t"   // j = med3(i, j, x)
        "v_med3_f32 %1, %2, %1, %10\n\t"   // i = med3(h, i, x)
        "v_med3_f32 %2, %3, %2, %10\n\t"   // h = med3(g, h, x)
        "v_med3_f32 %3, %4, %3, %10\n\t"   // g = med3(f, g, x)
        "v_med3_f32 %4, %5, %4, %10\n\t"   // f = med3(e, f, x)
        "v_med3_f32 %5, %6, %5, %10\n\t"   // e = med3(d, e, x)
        "v_med3_f32 %6, %7, %6, %10\n\t"   // d = med3(c, d, x)
        "v_med3_f32 %7, %8, %7, %10\n\t"   // c = med3(b, c, x)
        "v_med3_f32 %8, %9, %8, %10\n\t"   // b = med3(a, b, x)
        "v_min_f32  %9, %9, %10"           // a = min(a, x)
        : "+v"(L.j), "+v"(L.i), "+v"(L.h), "+v"(L.g), "+v"(L.f),
          "+v"(L.e), "+v"(L.d), "+v"(L.c), "+v"(L.b), "+v"(L.a)
        : "v"(x));
}
DEV void mergeX(L10& L, int d) {
    float ta=__shfl_xor(L.a,d), tb=__shfl_xor(L.b,d), tc=__shfl_xor(L.c,d);
    float td=__shfl_xor(L.d,d), te=__shfl_xor(L.e,d), tf=__shfl_xor(L.f,d);
    float tg=__shfl_xor(L.g,d), th=__shfl_xor(L.h,d), ti=__shfl_xor(L.i,d);
    float tj=__shfl_xor(L.j,d);
    ins(L,ta); ins(L,tb); ins(L,tc); ins(L,td); ins(L,te);
    ins(L,tf); ins(L,tg); ins(L,th); ins(L,ti); ins(L,tj);
}
// final-level merge: both lists sorted ascending -> lowest-10 of union is
// elementwise min(L[i], partner[9-i]) (bitonic property; output order scrambled).
DEV void mergeMin(L10& L, int d) {
    float ra=__shfl_xor(L.a,d), rb=__shfl_xor(L.b,d), rc=__shfl_xor(L.c,d);
    float rd_=__shfl_xor(L.d,d), re=__shfl_xor(L.e,d), rf=__shfl_xor(L.f,d);
    float rg=__shfl_xor(L.g,d), rh=__shfl_xor(L.h,d), ri=__shfl_xor(L.i,d);
    float rj=__shfl_xor(L.j,d);
    L.a=fminf(L.a,rj); L.b=fminf(L.b,ri); L.c=fminf(L.c,rh); L.d=fminf(L.d,rg);
    L.e=fminf(L.e,rf); L.f=fminf(L.f,re); L.g=fminf(L.g,rd_); L.h=fminf(L.h,rc);
    L.i=fminf(L.i,rb); L.j=fminf(L.j,ra);
}
DEV void storeL(const L10& L, float* dst) {
    dst[0]=L.a; dst[1]=L.b; dst[2]=L.c; dst[3]=L.d; dst[4]=L.e;
    dst[5]=L.f; dst[6]=L.g; dst[7]=L.h; dst[8]=L.i; dst[9]=L.j;
}

// ---------------- kernel 1: encoder ----------------
__global__ __launch_bounds__(128)
void k_encoder(const float* __restrict__ state, const float* __restrict__ W1,
               const float* __restrict__ b1, const float* __restrict__ W2,
               const float* __restrict__ b2, u16* __restrict__ encB,
               float* __restrict__ encN)
{
    __shared__ __align__(16) float sA[8][128];
    __shared__ __align__(16) float sH[8][128];
    const int tid = threadIdx.x;
    const int rbase = blockIdx.x * 8;

#pragma unroll
    for (int r = 0; r < 8; ++r)
        sA[r][tid] = state[(size_t)(rbase + r) * D + tid];
    __syncthreads();

    float acc[8];
#pragma unroll
    for (int r = 0; r < 8; ++r) acc[r] = b1[tid];
    for (int d4 = 0; d4 < 32; ++d4) {
        float w0 = W1[(d4 * 4 + 0) * D + tid];
        float w1 = W1[(d4 * 4 + 1) * D + tid];
        float w2 = W1[(d4 * 4 + 2) * D + tid];
        float w3 = W1[(d4 * 4 + 3) * D + tid];
#pragma unroll
        for (int r = 0; r < 8; ++r) {
            float4 sv = *reinterpret_cast<const float4*>(&sA[r][d4 * 4]);
            acc[r] = fmaf(sv.w, w3, fmaf(sv.z, w2, fmaf(sv.y, w1, fmaf(sv.x, w0, acc[r]))));
        }
    }
#pragma unroll
    for (int r = 0; r < 8; ++r) sH[r][tid] = fmaxf(acc[r], 0.f);
    __syncthreads();

#pragma unroll
    for (int r = 0; r < 8; ++r) acc[r] = b2[tid];
    for (int d4 = 0; d4 < 32; ++d4) {
        float w0 = W2[(d4 * 4 + 0) * D + tid];
        float w1 = W2[(d4 * 4 + 1) * D + tid];
        float w2 = W2[(d4 * 4 + 2) * D + tid];
        float w3 = W2[(d4 * 4 + 3) * D + tid];
#pragma unroll
        for (int r = 0; r < 8; ++r) {
            float4 sv = *reinterpret_cast<const float4*>(&sH[r][d4 * 4]);
            acc[r] = fmaf(sv.w, w3, fmaf(sv.z, w2, fmaf(sv.y, w1, fmaf(sv.x, w0, acc[r]))));
        }
    }

#pragma unroll
    for (int r = 0; r < 8; ++r) {
        u16 bb = f2bf(acc[r]);
        encB[(size_t)(rbase + r) * D + tid] = bb;
        float vv = bf2f(bb);
        sA[r][tid] = vv * vv;
    }
    __syncthreads();
    if (tid < 8) {
        float s = 0.f;
        for (int d = 0; d < 128; ++d) s += sA[tid][d];
        encN[rbase + tid] = s;
    }
}

// ---------------- kernel 2: memory -> bf16 + norms (+pad) ----------------
__global__ __launch_bounds__(256)
void k_memprep(const float* __restrict__ mem, u16* __restrict__ memB,
               float* __restrict__ memN)
{
    int g = blockIdx.x * 256 + threadIdx.x;
    int row = g >> 5;
    int l32 = g & 31;
    if (row >= CPAD) return;
    float4 v = make_float4(0.f, 0.f, 0.f, 0.f);
    bool real = row < C_REAL;
    if (real)
        v = *reinterpret_cast<const float4*>(mem + (size_t)row * D + l32 * 4);
    u16 c0 = f2bf(v.x), c1 = f2bf(v.y), c2 = f2bf(v.z), c3 = f2bf(v.w);
    float r0 = bf2f(c0), r1 = bf2f(c1), r2 = bf2f(c2), r3 = bf2f(c3);
    uint2 pk;
    pk.x = (unsigned)c0 | ((unsigned)c1 << 16);
    pk.y = (unsigned)c2 | ((unsigned)c3 << 16);
    *reinterpret_cast<uint2*>(memB + (size_t)row * D + l32 * 4) = pk;
    float s = r0 * r0 + r1 * r1 + r2 * r2 + r3 * r3;
    s += __shfl_xor(s, 16);
    s += __shfl_xor(s, 8);
    s += __shfl_xor(s, 4);
    s += __shfl_xor(s, 2);
    s += __shfl_xor(s, 1);
    if (l32 == 0) memN[row] = real ? s : __builtin_inff();
}

// ---------------- kernel 3: fused distance GEMM + per-split top-10 ----------------
// key per candidate = memN - 2*dot (encN added in k_final; same ordering per row)
// BM=128: 4 waves/block, 512 blocks = 2 blocks/CU -> independent barriers per
// block cover each other's staging drains (r6 was 1 block/CU, stall-bound).
__global__ __launch_bounds__(256)
__attribute__((amdgpu_waves_per_eu(2, 2)))
void k_dist(const u16* __restrict__ encB,
            const u16* __restrict__ memB, const float* __restrict__ memN,
            float* __restrict__ partials)
{
    __shared__ __align__(16) unsigned char btile[2][32768]; // double-buffered B chunk

    const int tid = threadIdx.x;
    const int w   = tid >> 6;        // wave 0..3
    const int l   = tid & 63;
    const int l15 = l & 15;
    const int lg  = l >> 4;          // 0..3
    const int split = blockIdx.x;    // 0..31
    const int rbase = blockIdx.y * BM;
    const long cbase0 = (long)split * (CHUNKS * BN);

    // A fragments (K=128) in registers: wave owns rows rbase + w*32 .. +31
    const u16* ap0 = encB + (size_t)(rbase + w * 32 + l15) * D;       // rf=0
    const u16* ap1 = encB + (size_t)(rbase + w * 32 + 16 + l15) * D;  // rf=1
    bf16x8 a00 = *reinterpret_cast<const bf16x8*>(ap0 + 0 * 32 + lg * 8);
    bf16x8 a01 = *reinterpret_cast<const bf16x8*>(ap0 + 1 * 32 + lg * 8);
    bf16x8 a02 = *reinterpret_cast<const bf16x8*>(ap0 + 2 * 32 + lg * 8);
    bf16x8 a03 = *reinterpret_cast<const bf16x8*>(ap0 + 3 * 32 + lg * 8);
    bf16x8 a10 = *reinterpret_cast<const bf16x8*>(ap1 + 0 * 32 + lg * 8);
    bf16x8 a11 = *reinterpret_cast<const bf16x8*>(ap1 + 1 * 32 + lg * 8);
    bf16x8 a12 = *reinterpret_cast<const bf16x8*>(ap1 + 2 * 32 + lg * 8);
    bf16x8 a13 = *reinterpret_cast<const bf16x8*>(ap1 + 3 * 32 + lg * 8);

    L10 T0,T1,T2,T3,T4,T5,T6,T7;
    linit(T0); linit(T1); linit(T2); linit(T3);
    linit(T4); linit(T5); linit(T6); linit(T7);

    // LDS content: LDS[x] = chunk[x ^ S(x)], S(x) = ((x>>8)&7)<<4 (involution;
    // S's input bits [10:8] are untouched by the XOR of bits [6:4]).
    // Staging via global_load_lds: LDS dest is wave-uniform base + lane*16
    // (linear), swizzle applied to the per-lane GLOBAL source address.
    // 256 threads x 16B = 4KB per call -> 8 calls cover the 32KB chunk.
    int wsrcoff[8];
#pragma unroll
    for (int u = 0; u < 8; ++u) {
        int p = (u << 12) | (tid << 4);
        wsrcoff[u] = p ^ (((p >> 8) & 7) << 4);
    }
    // read addresses: q = col*256 + ks*64 + lg*16, col = cg*16 + l15
    // LDS addr = q ^ ((col&7)<<4); per-lane base (cg=0), ks variants:
    const int rbl = ((l15 << 8) | (lg << 4)) ^ ((l15 & 7) << 4);
    const int off0 = rbl ^ (0 << 6);
    const int off1 = rbl ^ (1 << 6);
    const int off2 = rbl ^ (2 << 6);
    const int off3 = rbl ^ (3 << 6);

#define STAGE1(B, CH, U) \
    __builtin_amdgcn_global_load_lds( \
        (const __attribute__((address_space(1))) unsigned char*)(sb_ + wsrcoff[U]), \
        (__attribute__((address_space(3))) unsigned char*)(&btile[0][0] + (((B) << 15) | ((U) << 12) | (w << 10))), 16, 0, 0)

#define STAGE(B, CH) do { \
    const unsigned char* sb_ = (const unsigned char*)(memB + (cbase0 + (long)(CH) * BN) * D); \
    STAGE1(B, CH, 0); STAGE1(B, CH, 1); STAGE1(B, CH, 2); STAGE1(B, CH, 3); \
    STAGE1(B, CH, 4); STAGE1(B, CH, 5); STAGE1(B, CH, 6); STAGE1(B, CH, 7); \
} while (0)

#define KEY8(A0, A1, MN) do { \
    float k0_ = fmaf(-2.0f, (A0)[0], (MN)); \
    float k1_ = fmaf(-2.0f, (A0)[1], (MN)); \
    float k2_ = fmaf(-2.0f, (A0)[2], (MN)); \
    float k3_ = fmaf(-2.0f, (A0)[3], (MN)); \
    float k4_ = fmaf(-2.0f, (A1)[0], (MN)); \
    float k5_ = fmaf(-2.0f, (A1)[1], (MN)); \
    float k6_ = fmaf(-2.0f, (A1)[2], (MN)); \
    float k7_ = fmaf(-2.0f, (A1)[3], (MN)); \
    ins(T0, k0_); ins(T1, k1_); ins(T2, k2_); ins(T3, k3_); \
    ins(T4, k4_); ins(T5, k5_); ins(T6, k6_); ins(T7, k7_); \
} while (0)

#define DO_CG(CGI, MNV) do { \
    bf16x8 q0 = *reinterpret_cast<const bf16x8*>(bp + (off0 + ((CGI) << 12))); \
    bf16x8 q1 = *reinterpret_cast<const bf16x8*>(bp + (off1 + ((CGI) << 12))); \
    bf16x8 q2 = *reinterpret_cast<const bf16x8*>(bp + (off2 + ((CGI) << 12))); \
    bf16x8 q3 = *reinterpret_cast<const bf16x8*>(bp + (off3 + ((CGI) << 12))); \
    f32x4 ac0 = {0.f, 0.f, 0.f, 0.f}; \
    f32x4 ac1 = {0.f, 0.f, 0.f, 0.f}; \
    ac0 = MFMA(a00, q0, ac0, 0, 0, 0); \
    ac1 = MFMA(a10, q0, ac1, 0, 0, 0); \
    ac0 = MFMA(a01, q1, ac0, 0, 0, 0); \
    ac1 = MFMA(a11, q1, ac1, 0, 0, 0); \
    ac0 = MFMA(a02, q2, ac0, 0, 0, 0); \
    ac1 = MFMA(a12, q2, ac1, 0, 0, 0); \
    ac0 = MFMA(a03, q3, ac0, 0, 0, 0); \
    ac1 = MFMA(a13, q3, ac1, 0, 0, 0); \
    KEY8(ac0, ac1, (MNV)); \
} while (0)

    // prologue: stage chunk 0 into buffer 0; barrier drains vmcnt
    STAGE(0, 0);
    __syncthreads();

#pragma unroll 1
    for (int ch = 0; ch < CHUNKS; ++ch) {
        // issue next chunk's DMA into the other buffer (completes by the
        // barrier at the end of this iteration — a full chunk of cover)
        if (ch + 1 < CHUNKS) STAGE((ch + 1) & 1, ch + 1);

        const long cbase = cbase0 + (long)ch * BN;
        const float* mnp = memN + cbase + l15;
        float mn0 = mnp[0 * 16], mn1 = mnp[1 * 16], mn2 = mnp[2 * 16], mn3 = mnp[3 * 16];
        float mn4 = mnp[4 * 16], mn5 = mnp[5 * 16], mn6 = mnp[6 * 16], mn7 = mnp[7 * 16];

        const unsigned char* bp = &btile[ch & 1][0];
        DO_CG(0, mn0);
        DO_CG(1, mn1);
        DO_CG(2, mn2);
        DO_CG(3, mn3);
        DO_CG(4, mn4);
        DO_CG(5, mn5);
        DO_CG(6, mn6);
        DO_CG(7, mn7);
        __syncthreads();   // implicit s_waitcnt vmcnt(0): next buffer ready
    }

    // exact merge across the 16 col-lanes of each row: 3 insert-merge levels
    // (lists stay sorted) + 1 cheap min-level, then lane l15==0 stores.
#define MERGE_STORE(T, LI) do { \
    mergeX(T, 1); mergeX(T, 2); mergeX(T, 4); mergeMin(T, 8); \
    if (l15 == 0) { \
        int row = rbase + w * 32 + ((LI) >> 2) * 16 + lg * 4 + ((LI) & 3); \
        storeL(T, partials + (size_t)row * (NSPLIT * 10) + split * 10); \
    } \
} while (0)

    MERGE_STORE(T0, 0);
    MERGE_STORE(T1, 1);
    MERGE_STORE(T2, 2);
    MERGE_STORE(T3, 3);
    MERGE_STORE(T4, 4);
    MERGE_STORE(T5, 5);
    MERGE_STORE(T6, 6);
    MERGE_STORE(T7, 7);
}

// ---------------- kernel 4: final merge + mean of sqrt (1 wave / row) ----------------
__global__ __launch_bounds__(256)
void k_final(const float* __restrict__ partials, const float* __restrict__ encN,
             float* __restrict__ out)
{
    const int w = threadIdx.x >> 6;
    const int l = threadIdx.x & 63;
    const int row = blockIdx.x * 4 + w;

    L10 L;
    linit(L);
    const float* p = partials + (size_t)row * (NSPLIT * 10) + l * 5;
    ins(L, p[0]); ins(L, p[1]); ins(L, p[2]); ins(L, p[3]); ins(L, p[4]);
    mergeX(L, 1); mergeX(L, 2); mergeX(L, 4);
    mergeX(L, 8); mergeX(L, 16); mergeMin(L, 32);
    if (l == 0) {
        float en = encN[row];
        float s = 0.f;
        s += sqrtf(fmaxf(en + L.a, 1e-12f));
        s += sqrtf(fmaxf(en + L.b, 1e-12f));
        s += sqrtf(fmaxf(en + L.c, 1e-12f));
        s += sqrtf(fmaxf(en + L.d, 1e-12f));
        s += sqrtf(fmaxf(en + L.e, 1e-12f));
        s += sqrtf(fmaxf(en + L.f, 1e-12f));
        s += sqrtf(fmaxf(en + L.g, 1e-12f));
        s += sqrtf(fmaxf(en + L.h, 1e-12f));
        s += sqrtf(fmaxf(en + L.i, 1e-12f));
        s += sqrtf(fmaxf(en + L.j, 1e-12f));
        out[row] = s * 0.1f;
    }
}

extern "C" void kernel_launch(void* const* d_in, const int* in_sizes, int n_in,
                              void* d_out, int out_size, void* d_ws, size_t ws_size,
                              hipStream_t stream)
{
    const float* state = (const float*)d_in[0];
    const float* W1    = (const float*)d_in[1];
    const float* b1    = (const float*)d_in[2];
    const float* W2    = (const float*)d_in[3];
    const float* b2    = (const float*)d_in[4];
    const float* mem   = (const float*)d_in[5];
    float* out = (float*)d_out;
    char* ws = (char*)d_ws;
    u16*   memB = (u16*)(ws + OFF_MEMB);
    float* memN = (float*)(ws + OFF_MEMN);
    u16*   encB = (u16*)(ws + OFF_ENCB);
    float* encN = (float*)(ws + OFF_ENCN);
    float* partials = (float*)(ws + OFF_PART);

    hipLaunchKernelGGL(k_encoder, dim3(NB / 8), dim3(128), 0, stream,
                       state, W1, b1, W2, b2, encB, encN);
    hipLaunchKernelGGL(k_memprep, dim3(CPAD * 32 / 256), dim3(256), 0, stream,
                       mem, memB, memN);
    hipLaunchKernelGGL(k_dist, dim3(NSPLIT, NB / BM), dim3(256), 0, stream,
                       encB, memB, memN, partials);
    hipLaunchKernelGGL(k_final, dim3(NB / 4), dim3(256), 0, stream,
                       partials, encN, out);
}